// Round 16
// baseline (108.809 us; speedup 1.0000x reference)
//
#include <hip/hip_runtime.h>

#define T_LEN 50
#define CH_A 26          // chunk A steps (slots 0..25)
#define CH_B 24          // chunk B steps (t=26..49 -> slots 0..23)

typedef __fp16 fp16x8 __attribute__((ext_vector_type(8)));
typedef float f32x16 __attribute__((ext_vector_type(16)));
typedef unsigned int uint4v __attribute__((ext_vector_type(4)));

__device__ __forceinline__ float EXP2(float x){ return __builtin_amdgcn_exp2f(x); }
__device__ __forceinline__ float RCP(float x){ return __builtin_amdgcn_rcpf(x); }
__device__ __forceinline__ unsigned PKU(float a, float b){
    return __builtin_bit_cast(unsigned, __builtin_amdgcn_cvt_pkrtz(a, b));
}

// LSTM pointwise stage for one (layer, unit, element). Gates pre-scaled:
// i,f,o by S1=-log2e; g by S2=-2log2e (folded into weights+bias).
__device__ __forceinline__ void act(float gi, float gf, float gg, float go,
                                    float& c, float& h){
    const float S2 = -2.8853900817779268f;
    const float p = EXP2(gi);
    const float r = EXP2(gf);
    const float q = EXP2(gg);
    const float s = EXP2(go);
    const float A  = 1.0f + r;
    const float BC = (1.0f + p) * (1.0f + q);
    const float num = fmaf(c, BC, (1.0f - q) * A);
    c = num * RCP(A * BC);
    const float u = EXP2(fminf(c * S2, 96.0f));
    h = (1.0f - u) * RCP((1.0f + s) * (1.0f + u));
}

// Wave tile: 32 elements. One mfma_f32_32x32x16_f16 per step: L0 gates(t) rows 0-15,
// L1 gates(t-1) rows 16-31. B = [x(t) k0-1 | h0 k2-5 | h1 k6-9 | 0]. Bias in C.
// x staged as packed-f16 u32 in wave-private LDS, 2 chunks for occupancy.
__global__ __launch_bounds__(256, 8) void lstm_mfma32(
    const float* __restrict__ x,
    const float* __restrict__ Wih0, const float* __restrict__ Whh0,
    const float* __restrict__ bih0, const float* __restrict__ bhh0,
    const float* __restrict__ Wih1, const float* __restrict__ Whh1,
    const float* __restrict__ bih1, const float* __restrict__ bhh1,
    const float* __restrict__ Wout, const float* __restrict__ bout,
    float* __restrict__ out, int B)
{
    __shared__ float2 wout_s[T_LEN*2];            // [t][h]=(W[t*4+h],W[t*4+h+2])
    __shared__ unsigned xstage[4*32*CH_A];        // packed f16 x, per-wave regions
    const int tid = threadIdx.x;
    if (tid < T_LEN*2){
        const int t = tid >> 1, hh = tid & 1;
        wout_s[tid] = make_float2(Wout[t*4+hh], Wout[t*4+hh+2]);
    }
    __syncthreads();

    const int lane = tid & 63;
    const int e = lane & 31;          // element column
    const int h = lane >> 5;          // half: owns units {h, 2+h} per layer
    const int wslot = tid >> 6;
    const int wave = (blockIdx.x*256 + tid) >> 6;
    const int E0 = wave * 32;
    if (E0 >= B) return;

    unsigned* xr = xstage + wslot * (32*CH_A);

    const float S1 = -1.4426950408889634f;
    const float S2 = -2.8853900817779268f;

    // ---- A fragment: lane supplies row mA=e, k=8h+0..7 ----
    const int qA = e >> 2, tA = e & 3;
    const float sA = (tA == 2) ? S2 : S1;
    uint4v au;
#pragma unroll
    for (int p = 0; p < 4; ++p){
        float vv[2];
#pragma unroll
        for (int z = 0; z < 2; ++z){
            const int k = 8*h + 2*p + z;
            float v = 0.f;
            if (qA < 4){                          // L0 rows: x(k0-1), h0(k2-5)
                const int r = tA*4 + qA;
                if (k < 2)      v = Wih0[r*2 + k];
                else if (k < 6) v = Whh0[r*4 + (k-2)];
            } else {                              // L1 rows: h0(k2-5), h1(k6-9)
                const int r = tA*4 + (qA-4);
                if (k >= 2 && k < 6)       v = Wih1[r*4 + (k-2)];
                else if (k >= 6 && k < 10) v = Whh1[r*4 + (k-6)];
            }
            vv[z] = v * sA;
        }
        au[p] = PKU(vv[0], vv[1]);
    }
    const fp16x8 Afrag = __builtin_bit_cast(fp16x8, au);

    // ---- bias as C operand (loop-invariant) ----
    f32x16 biasC;
#pragma unroll
    for (int r = 0; r < 16; ++r){
        const int m = (r&3) + 8*(r>>2) + 4*h;
        const int q = m >> 2, tg = m & 3;
        const float st = (tg == 2) ? S2 : S1;
        if (q < 4){ const int rr = tg*4 + q;      biasC[r] = (bih0[rr]+bhh0[rr])*st; }
        else      { const int rr = tg*4 + (q-4);  biasC[r] = (bih1[rr]+bhh1[rr])*st; }
    }

    const float* xg = x + (size_t)E0 * (T_LEN*2);

    // ---- stage chunk A (t=0..25): 832 u32 = 13 per lane, coalesced float2 ----
#pragma unroll
    for (int k = 0; k < 13; ++k){
        const int i = 64*k + lane;
        const int e_ = i / CH_A, t_ = i % CH_A;
        const float2 v = *reinterpret_cast<const float2*>(xg + e_*100 + t_*2);
        xr[e_*CH_A + t_] = PKU(v.x, v.y);
    }
    // ---- prefetch chunk B (t=26..49) into registers (768 u32 = 12 per lane) ----
    unsigned rbp[12];
#pragma unroll
    for (int k = 0; k < 12; ++k){
        const int i = 64*k + lane;
        const int e_ = i / CH_B, t_ = i % CH_B;
        const float2 v = *reinterpret_cast<const float2*>(xg + e_*100 + (26 + t_)*2);
        rbp[k] = PKU(v.x, v.y);
    }

    float c0l=0.f, c0h=0.f, c1l=0.f, c1h=0.f, acc=0.f;
    unsigned pk_h0_01=0u, pk_h0_23=0u, pk_h1_01=0u, pk_h1_23=0u;

    auto mainstep = [&](int t, unsigned ux){
        uint4v bu;
        bu[0] = h ? pk_h1_23 : ux;
        bu[1] = pk_h0_01;
        bu[2] = pk_h0_23;
        bu[3] = pk_h1_01;
        const f32x16 d = __builtin_amdgcn_mfma_f32_32x32x16_f16(
            Afrag, __builtin_bit_cast(fp16x8, bu), biasC, 0, 0, 0);
        float h0l,h0h,h1l,h1h;
        act(d[0], d[1], d[2], d[3],  c0l, h0l);
        act(d[4], d[5], d[6], d[7],  c0h, h0h);
        act(d[8], d[9], d[10],d[11], c1l, h1l);
        act(d[12],d[13],d[14],d[15], c1h, h1h);
        const float2 wo = wout_s[(t-1)*2 + h];
        acc = fmaf(h1l, wo.x, fmaf(h1h, wo.y, acc));
        const float r0l = __shfl_xor(h0l,32,64), r0h = __shfl_xor(h0h,32,64);
        const float r1l = __shfl_xor(h1l,32,64), r1h = __shfl_xor(h1h,32,64);
        pk_h0_01 = PKU(h0l, r0l);
        pk_h0_23 = PKU(h0h, r0h);
        pk_h1_01 = PKU(h1l, r1l);
        pk_h1_23 = PKU(r1h, h1h);
    };

    // ---- prologue t=0: L0 only ----
    {
        const unsigned ux = xr[e*CH_A + 0];
        uint4v bu; bu[0] = h ? 0u : ux; bu[1]=0u; bu[2]=0u; bu[3]=0u;
        const f32x16 d = __builtin_amdgcn_mfma_f32_32x32x16_f16(
            Afrag, __builtin_bit_cast(fp16x8, bu), biasC, 0, 0, 0);
        float h0l, h0h;
        act(d[0],d[1],d[2],d[3], c0l, h0l);
        act(d[4],d[5],d[6],d[7], c0h, h0h);
        const float r0l = __shfl_xor(h0l, 32, 64);
        const float r0h = __shfl_xor(h0h, 32, 64);
        pk_h0_01 = PKU(h0l, r0l);
        pk_h0_23 = PKU(h0h, r0h);
    }

    for (int t = 1; t < 26; ++t)
        mainstep(t, xr[e*CH_A + t]);

    // write chunk B over slots 0..23 (chunk A reads already issued; DS in-order)
#pragma unroll
    for (int k = 0; k < 12; ++k){
        const int i = 64*k + lane;
        const int e_ = i / CH_B, t_ = i % CH_B;
        xr[e_*CH_A + t_] = rbp[k];
    }
    for (int t = 26; t < T_LEN; ++t)
        mainstep(t, xr[e*CH_A + (t - 26)]);

    // ---- epilogue: L1 at t=49 ----
    {
        uint4v bu;
        bu[0] = h ? pk_h1_23 : 0u;
        bu[1] = pk_h0_01; bu[2] = pk_h0_23; bu[3] = pk_h1_01;
        const f32x16 d = __builtin_amdgcn_mfma_f32_32x32x16_f16(
            Afrag, __builtin_bit_cast(fp16x8, bu), biasC, 0, 0, 0);
        float h1l, h1h;
        act(d[8], d[9], d[10],d[11], c1l, h1l);
        act(d[12],d[13],d[14],d[15], c1h, h1h);
        const float2 wo = wout_s[49*2 + h];
        acc = fmaf(h1l, wo.x, fmaf(h1h, wo.y, acc));
    }

    acc += __shfl_xor(acc, 32, 64);
    if (h == 0){
        const float z = acc + bout[0];
        out[E0 + e] = RCP(1.0f + EXP2(z * S1));   // sigmoid
    }
}

extern "C" void kernel_launch(void* const* d_in, const int* in_sizes, int n_in,
                              void* d_out, int out_size, void* d_ws, size_t ws_size,
                              hipStream_t stream)
{
    const float* x    = (const float*)d_in[0];
    const float* Wih0 = (const float*)d_in[1];
    const float* Whh0 = (const float*)d_in[2];
    const float* bih0 = (const float*)d_in[3];
    const float* bhh0 = (const float*)d_in[4];
    const float* Wih1 = (const float*)d_in[5];
    const float* Whh1 = (const float*)d_in[6];
    const float* bih1 = (const float*)d_in[7];
    const float* bhh1 = (const float*)d_in[8];
    const float* Wout = (const float*)d_in[9];
    const float* bout = (const float*)d_in[10];
    float* out = (float*)d_out;

    const int B = in_sizes[0] / (T_LEN*2);
    const int waves = (B + 31) / 32;
    const int blocks = (waves + 3) / 4;       // 4 waves per 256-thread block
    lstm_mfma32<<<blocks, 256, 0, stream>>>(x, Wih0, Whh0, bih0, bhh0,
                                            Wih1, Whh1, bih1, bhh1,
                                            Wout, bout, out, B);
}

// Round 17
// 100.309 us; speedup vs baseline: 1.0847x; 1.0847x over previous
//
#include <hip/hip_runtime.h>

#define T_LEN 50
#define CH_A 26          // chunk A steps (slots 0..25)
#define CH_B 24          // chunk B steps (t=26..49 -> slots 0..23)

typedef __fp16 fp16x8 __attribute__((ext_vector_type(8)));
typedef float f32x16 __attribute__((ext_vector_type(16)));
typedef unsigned int uint4v __attribute__((ext_vector_type(4)));

__device__ __forceinline__ float EXP2(float x){ return __builtin_amdgcn_exp2f(x); }
__device__ __forceinline__ float RCP(float x){ return __builtin_amdgcn_rcpf(x); }
__device__ __forceinline__ unsigned PKU(float a, float b){
    return __builtin_bit_cast(unsigned, __builtin_amdgcn_cvt_pkrtz(a, b));
}

// LSTM pointwise stage for one (layer, unit, element). Gates pre-scaled:
// i,f,o by S1=-log2e; g by S2=-2log2e (folded into weights+bias).
__device__ __forceinline__ void act(float gi, float gf, float gg, float go,
                                    float& c, float& h){
    const float S2 = -2.8853900817779268f;
    const float p = EXP2(gi);
    const float r = EXP2(gf);
    const float q = EXP2(gg);
    const float s = EXP2(go);
    const float A  = 1.0f + r;
    const float BC = (1.0f + p) * (1.0f + q);
    const float num = fmaf(c, BC, (1.0f - q) * A);
    c = num * RCP(A * BC);
    const float u = EXP2(fminf(c * S2, 96.0f));
    h = (1.0f - u) * RCP((1.0f + s) * (1.0f + u));
}

// Wave tile: 32 elements. One mfma_f32_32x32x16_f16 per step: L0 gates(t) rows 0-15,
// L1 gates(t-1) rows 16-31. B = [x(t) k0-1 | h0 k2-5 | h1 k6-9 | 0]. Bias in C.
// x staged as packed-f16 u32 in wave-private LDS, 2 chunks (13.3 KB) so the
// 2048-thread/CU cap (8 blocks) — not LDS — bounds occupancy.
// launch_bounds(256,6): VGPR cap ~85 -> no scratch spill (r16's (256,8) spilled).
__global__ __launch_bounds__(256, 6) void lstm_mfma32(
    const float* __restrict__ x,
    const float* __restrict__ Wih0, const float* __restrict__ Whh0,
    const float* __restrict__ bih0, const float* __restrict__ bhh0,
    const float* __restrict__ Wih1, const float* __restrict__ Whh1,
    const float* __restrict__ bih1, const float* __restrict__ bhh1,
    const float* __restrict__ Wout, const float* __restrict__ bout,
    float* __restrict__ out, int B)
{
    __shared__ float2 wout_s[T_LEN*2];            // [t][h]=(W[t*4+h],W[t*4+h+2])
    __shared__ unsigned xstage[4*32*CH_A];        // packed f16 x, per-wave regions
    const int tid = threadIdx.x;
    if (tid < T_LEN*2){
        const int t = tid >> 1, hh = tid & 1;
        wout_s[tid] = make_float2(Wout[t*4+hh], Wout[t*4+hh+2]);
    }
    __syncthreads();

    const int lane = tid & 63;
    const int e = lane & 31;          // element column
    const int h = lane >> 5;          // half: owns units {h, 2+h} per layer
    const int wslot = tid >> 6;
    const int wave = (blockIdx.x*256 + tid) >> 6;
    const int E0 = wave * 32;
    if (E0 >= B) return;

    unsigned* xr = xstage + wslot * (32*CH_A);

    const float S1 = -1.4426950408889634f;
    const float S2 = -2.8853900817779268f;

    // ---- A fragment: lane supplies row mA=e, k=8h+0..7 ----
    const int qA = e >> 2, tA = e & 3;
    const float sA = (tA == 2) ? S2 : S1;
    uint4v au;
#pragma unroll
    for (int p = 0; p < 4; ++p){
        float vv[2];
#pragma unroll
        for (int z = 0; z < 2; ++z){
            const int k = 8*h + 2*p + z;
            float v = 0.f;
            if (qA < 4){                          // L0 rows: x(k0-1), h0(k2-5)
                const int r = tA*4 + qA;
                if (k < 2)      v = Wih0[r*2 + k];
                else if (k < 6) v = Whh0[r*4 + (k-2)];
            } else {                              // L1 rows: h0(k2-5), h1(k6-9)
                const int r = tA*4 + (qA-4);
                if (k >= 2 && k < 6)       v = Wih1[r*4 + (k-2)];
                else if (k >= 6 && k < 10) v = Whh1[r*4 + (k-6)];
            }
            vv[z] = v * sA;
        }
        au[p] = PKU(vv[0], vv[1]);
    }
    const fp16x8 Afrag = __builtin_bit_cast(fp16x8, au);

    // ---- bias as C operand (loop-invariant) ----
    f32x16 biasC;
#pragma unroll
    for (int r = 0; r < 16; ++r){
        const int m = (r&3) + 8*(r>>2) + 4*h;
        const int q = m >> 2, tg = m & 3;
        const float st = (tg == 2) ? S2 : S1;
        if (q < 4){ const int rr = tg*4 + q;      biasC[r] = (bih0[rr]+bhh0[rr])*st; }
        else      { const int rr = tg*4 + (q-4);  biasC[r] = (bih1[rr]+bhh1[rr])*st; }
    }

    const float* xg = x + (size_t)E0 * (T_LEN*2);

    // ---- stage chunk A (t=0..25): 832 u32 = 13 per lane, coalesced float2 ----
#pragma unroll
    for (int k = 0; k < 13; ++k){
        const int i = 64*k + lane;
        const int e_ = i / CH_A, t_ = i % CH_A;
        const float2 v = *reinterpret_cast<const float2*>(xg + e_*100 + t_*2);
        xr[e_*CH_A + t_] = PKU(v.x, v.y);
    }
    // ---- prefetch chunk B (t=26..49) into registers (768 u32 = 12 per lane) ----
    unsigned rbp[12];
#pragma unroll
    for (int k = 0; k < 12; ++k){
        const int i = 64*k + lane;
        const int e_ = i / CH_B, t_ = i % CH_B;
        const float2 v = *reinterpret_cast<const float2*>(xg + e_*100 + (26 + t_)*2);
        rbp[k] = PKU(v.x, v.y);
    }

    float c0l=0.f, c0h=0.f, c1l=0.f, c1h=0.f, acc=0.f;
    unsigned pk_h0_01=0u, pk_h0_23=0u, pk_h1_01=0u, pk_h1_23=0u;

    auto mainstep = [&](int t, unsigned ux){
        uint4v bu;
        bu[0] = h ? pk_h1_23 : ux;
        bu[1] = pk_h0_01;
        bu[2] = pk_h0_23;
        bu[3] = pk_h1_01;
        const f32x16 d = __builtin_amdgcn_mfma_f32_32x32x16_f16(
            Afrag, __builtin_bit_cast(fp16x8, bu), biasC, 0, 0, 0);
        float h0l,h0h,h1l,h1h;
        act(d[0], d[1], d[2], d[3],  c0l, h0l);
        act(d[4], d[5], d[6], d[7],  c0h, h0h);
        act(d[8], d[9], d[10],d[11], c1l, h1l);
        act(d[12],d[13],d[14],d[15], c1h, h1h);
        const float2 wo = wout_s[(t-1)*2 + h];
        acc = fmaf(h1l, wo.x, fmaf(h1h, wo.y, acc));
        const float r0l = __shfl_xor(h0l,32,64), r0h = __shfl_xor(h0h,32,64);
        const float r1l = __shfl_xor(h1l,32,64), r1h = __shfl_xor(h1h,32,64);
        pk_h0_01 = PKU(h0l, r0l);
        pk_h0_23 = PKU(h0h, r0h);
        pk_h1_01 = PKU(h1l, r1l);
        pk_h1_23 = PKU(r1h, h1h);
    };

    // ---- prologue t=0: L0 only ----
    {
        const unsigned ux = xr[e*CH_A + 0];
        uint4v bu; bu[0] = h ? 0u : ux; bu[1]=0u; bu[2]=0u; bu[3]=0u;
        const f32x16 d = __builtin_amdgcn_mfma_f32_32x32x16_f16(
            Afrag, __builtin_bit_cast(fp16x8, bu), biasC, 0, 0, 0);
        float h0l, h0h;
        act(d[0],d[1],d[2],d[3], c0l, h0l);
        act(d[4],d[5],d[6],d[7], c0h, h0h);
        const float r0l = __shfl_xor(h0l, 32, 64);
        const float r0h = __shfl_xor(h0h, 32, 64);
        pk_h0_01 = PKU(h0l, r0l);
        pk_h0_23 = PKU(h0h, r0h);
    }

    for (int t = 1; t < 26; ++t)
        mainstep(t, xr[e*CH_A + t]);

    // write chunk B over slots 0..23 (chunk A reads already issued; DS in-order)
#pragma unroll
    for (int k = 0; k < 12; ++k){
        const int i = 64*k + lane;
        const int e_ = i / CH_B, t_ = i % CH_B;
        xr[e_*CH_A + t_] = rbp[k];
    }
    for (int t = 26; t < T_LEN; ++t)
        mainstep(t, xr[e*CH_A + (t - 26)]);

    // ---- epilogue: L1 at t=49 ----
    {
        uint4v bu;
        bu[0] = h ? pk_h1_23 : 0u;
        bu[1] = pk_h0_01; bu[2] = pk_h0_23; bu[3] = pk_h1_01;
        const f32x16 d = __builtin_amdgcn_mfma_f32_32x32x16_f16(
            Afrag, __builtin_bit_cast(fp16x8, bu), biasC, 0, 0, 0);
        float h1l, h1h;
        act(d[8], d[9], d[10],d[11], c1l, h1l);
        act(d[12],d[13],d[14],d[15], c1h, h1h);
        const float2 wo = wout_s[49*2 + h];
        acc = fmaf(h1l, wo.x, fmaf(h1h, wo.y, acc));
    }

    acc += __shfl_xor(acc, 32, 64);
    if (h == 0){
        const float z = acc + bout[0];
        out[E0 + e] = RCP(1.0f + EXP2(z * S1));   // sigmoid
    }
}

extern "C" void kernel_launch(void* const* d_in, const int* in_sizes, int n_in,
                              void* d_out, int out_size, void* d_ws, size_t ws_size,
                              hipStream_t stream)
{
    const float* x    = (const float*)d_in[0];
    const float* Wih0 = (const float*)d_in[1];
    const float* Whh0 = (const float*)d_in[2];
    const float* bih0 = (const float*)d_in[3];
    const float* bhh0 = (const float*)d_in[4];
    const float* Wih1 = (const float*)d_in[5];
    const float* Whh1 = (const float*)d_in[6];
    const float* bih1 = (const float*)d_in[7];
    const float* bhh1 = (const float*)d_in[8];
    const float* Wout = (const float*)d_in[9];
    const float* bout = (const float*)d_in[10];
    float* out = (float*)d_out;

    const int B = in_sizes[0] / (T_LEN*2);
    const int waves = (B + 31) / 32;
    const int blocks = (waves + 3) / 4;       // 4 waves per 256-thread block
    lstm_mfma32<<<blocks, 256, 0, stream>>>(x, Wih0, Whh0, bih0, bhh0,
                                            Wih1, Whh1, bih1, bhh1,
                                            Wout, bout, out, B);
}

// Round 18
// 92.366 us; speedup vs baseline: 1.1780x; 1.0860x over previous
//
#include <hip/hip_runtime.h>

#define T_LEN 50

typedef __fp16 fp16x8 __attribute__((ext_vector_type(8)));
typedef float f32x16 __attribute__((ext_vector_type(16)));
typedef unsigned int uint4v __attribute__((ext_vector_type(4)));

__device__ __forceinline__ float EXP2(float x){ return __builtin_amdgcn_exp2f(x); }
__device__ __forceinline__ float RCP(float x){ return __builtin_amdgcn_rcpf(x); }
__device__ __forceinline__ unsigned PKU(float a, float b){
    return __builtin_bit_cast(unsigned, __builtin_amdgcn_cvt_pkrtz(a, b));
}

// LSTM pointwise stage for one (layer, unit, element). Gates pre-scaled:
// i,f,o by S1=-log2e; g by S2=-2log2e (folded into weights+bias).
__device__ __forceinline__ void act(float gi, float gf, float gg, float go,
                                    float& c, float& h){
    const float S2 = -2.8853900817779268f;
    const float p = EXP2(gi);
    const float r = EXP2(gf);
    const float q = EXP2(gg);
    const float s = EXP2(go);
    const float A  = 1.0f + r;
    const float BC = (1.0f + p) * (1.0f + q);
    const float num = fmaf(c, BC, (1.0f - q) * A);
    c = num * RCP(A * BC);
    const float u = EXP2(fminf(c * S2, 96.0f));
    h = (1.0f - u) * RCP((1.0f + s) * (1.0f + u));
}

// Wave tile: 32 elements. One mfma_f32_32x32x16_f16 per step: L0 gates(t) rows 0-15,
// L1 gates(t-1) rows 16-31. B = [x(t) k0-1 | h0 k2-5 | h1 k6-9 | 0]. Bias in C.
// x staged once, fully (50 steps), as packed-f16 u32 in wave-private LDS:
// no register-resident chunk -> no scratch spill (r14-r17's 35-83 MB WRITE_SIZE).
// Stride-50 dword access: 18e mod 32 -> 2-way bank alias = free.
__global__ __launch_bounds__(256, 6) void lstm_mfma32(
    const float* __restrict__ x,
    const float* __restrict__ Wih0, const float* __restrict__ Whh0,
    const float* __restrict__ bih0, const float* __restrict__ bhh0,
    const float* __restrict__ Wih1, const float* __restrict__ Whh1,
    const float* __restrict__ bih1, const float* __restrict__ bhh1,
    const float* __restrict__ Wout, const float* __restrict__ bout,
    float* __restrict__ out, int B)
{
    __shared__ float2 wout_s[T_LEN*2];            // [t][h]=(W[t*4+h],W[t*4+h+2])
    __shared__ unsigned xstage[4*32*T_LEN];       // packed f16 x, per-wave regions
    const int tid = threadIdx.x;
    if (tid < T_LEN*2){
        const int t = tid >> 1, hh = tid & 1;
        wout_s[tid] = make_float2(Wout[t*4+hh], Wout[t*4+hh+2]);
    }
    __syncthreads();

    const int lane = tid & 63;
    const int e = lane & 31;          // element column
    const int h = lane >> 5;          // half: owns units {h, 2+h} per layer
    const int wslot = tid >> 6;
    const int wave = (blockIdx.x*256 + tid) >> 6;
    const int E0 = wave * 32;
    if (E0 >= B) return;

    unsigned* xr = xstage + wslot * (32*T_LEN);

    const float S1 = -1.4426950408889634f;
    const float S2 = -2.8853900817779268f;

    // ---- A fragment: lane supplies row mA=e, k=8h+0..7 ----
    const int qA = e >> 2, tA = e & 3;
    const float sA = (tA == 2) ? S2 : S1;
    uint4v au;
#pragma unroll
    for (int p = 0; p < 4; ++p){
        float vv[2];
#pragma unroll
        for (int z = 0; z < 2; ++z){
            const int k = 8*h + 2*p + z;
            float v = 0.f;
            if (qA < 4){                          // L0 rows: x(k0-1), h0(k2-5)
                const int r = tA*4 + qA;
                if (k < 2)      v = Wih0[r*2 + k];
                else if (k < 6) v = Whh0[r*4 + (k-2)];
            } else {                              // L1 rows: h0(k2-5), h1(k6-9)
                const int r = tA*4 + (qA-4);
                if (k >= 2 && k < 6)       v = Wih1[r*4 + (k-2)];
                else if (k >= 6 && k < 10) v = Whh1[r*4 + (k-6)];
            }
            vv[z] = v * sA;
        }
        au[p] = PKU(vv[0], vv[1]);
    }
    const fp16x8 Afrag = __builtin_bit_cast(fp16x8, au);

    // ---- bias as C operand (loop-invariant) ----
    f32x16 biasC;
#pragma unroll
    for (int r = 0; r < 16; ++r){
        const int m = (r&3) + 8*(r>>2) + 4*h;
        const int q = m >> 2, tg = m & 3;
        const float st = (tg == 2) ? S2 : S1;
        if (q < 4){ const int rr = tg*4 + q;      biasC[r] = (bih0[rr]+bhh0[rr])*st; }
        else      { const int rr = tg*4 + (q-4);  biasC[r] = (bih1[rr]+bhh1[rr])*st; }
    }

    const float* xg = x + (size_t)E0 * (T_LEN*2);

    // ---- stage all 50 steps: 1600 u32 = 25 per lane, coalesced float2 loads ----
#pragma unroll
    for (int k = 0; k < 25; ++k){
        const int i = 64*k + lane;
        const int e_ = i / T_LEN, t_ = i % T_LEN;
        const float2 v = *reinterpret_cast<const float2*>(xg + e_*100 + t_*2);
        xr[e_*T_LEN + t_] = PKU(v.x, v.y);
    }

    float c0l=0.f, c0h=0.f, c1l=0.f, c1h=0.f, acc=0.f;
    unsigned pk_h0_01=0u, pk_h0_23=0u, pk_h1_01=0u, pk_h1_23=0u;

    auto mainstep = [&](int t, unsigned ux){
        uint4v bu;
        bu[0] = h ? pk_h1_23 : ux;
        bu[1] = pk_h0_01;
        bu[2] = pk_h0_23;
        bu[3] = pk_h1_01;
        const f32x16 d = __builtin_amdgcn_mfma_f32_32x32x16_f16(
            Afrag, __builtin_bit_cast(fp16x8, bu), biasC, 0, 0, 0);
        float h0l,h0h,h1l,h1h;
        act(d[0], d[1], d[2], d[3],  c0l, h0l);
        act(d[4], d[5], d[6], d[7],  c0h, h0h);
        act(d[8], d[9], d[10],d[11], c1l, h1l);
        act(d[12],d[13],d[14],d[15], c1h, h1h);
        const float2 wo = wout_s[(t-1)*2 + h];
        acc = fmaf(h1l, wo.x, fmaf(h1h, wo.y, acc));
        const float r0l = __shfl_xor(h0l,32,64), r0h = __shfl_xor(h0h,32,64);
        const float r1l = __shfl_xor(h1l,32,64), r1h = __shfl_xor(h1h,32,64);
        pk_h0_01 = PKU(h0l, r0l);
        pk_h0_23 = PKU(h0h, r0h);
        pk_h1_01 = PKU(h1l, r1l);
        pk_h1_23 = PKU(r1h, h1h);
    };

    // ---- prologue t=0: L0 only ----
    {
        const unsigned ux = xr[e*T_LEN + 0];
        uint4v bu; bu[0] = h ? 0u : ux; bu[1]=0u; bu[2]=0u; bu[3]=0u;
        const f32x16 d = __builtin_amdgcn_mfma_f32_32x32x16_f16(
            Afrag, __builtin_bit_cast(fp16x8, bu), biasC, 0, 0, 0);
        float h0l, h0h;
        act(d[0],d[1],d[2],d[3], c0l, h0l);
        act(d[4],d[5],d[6],d[7], c0h, h0h);
        const float r0l = __shfl_xor(h0l, 32, 64);
        const float r0h = __shfl_xor(h0h, 32, 64);
        pk_h0_01 = PKU(h0l, r0l);
        pk_h0_23 = PKU(h0h, r0h);
    }

    for (int t = 1; t < T_LEN; ++t)
        mainstep(t, xr[e*T_LEN + t]);

    // ---- epilogue: L1 at t=49 ----
    {
        uint4v bu;
        bu[0] = h ? pk_h1_23 : 0u;
        bu[1] = pk_h0_01; bu[2] = pk_h0_23; bu[3] = pk_h1_01;
        const f32x16 d = __builtin_amdgcn_mfma_f32_32x32x16_f16(
            Afrag, __builtin_bit_cast(fp16x8, bu), biasC, 0, 0, 0);
        float h1l, h1h;
        act(d[8], d[9], d[10],d[11], c1l, h1l);
        act(d[12],d[13],d[14],d[15], c1h, h1h);
        const float2 wo = wout_s[49*2 + h];
        acc = fmaf(h1l, wo.x, fmaf(h1h, wo.y, acc));
    }

    acc += __shfl_xor(acc, 32, 64);
    if (h == 0){
        const float z = acc + bout[0];
        out[E0 + e] = RCP(1.0f + EXP2(z * S1));   // sigmoid
    }
}

extern "C" void kernel_launch(void* const* d_in, const int* in_sizes, int n_in,
                              void* d_out, int out_size, void* d_ws, size_t ws_size,
                              hipStream_t stream)
{
    const float* x    = (const float*)d_in[0];
    const float* Wih0 = (const float*)d_in[1];
    const float* Whh0 = (const float*)d_in[2];
    const float* bih0 = (const float*)d_in[3];
    const float* bhh0 = (const float*)d_in[4];
    const float* Wih1 = (const float*)d_in[5];
    const float* Whh1 = (const float*)d_in[6];
    const float* bih1 = (const float*)d_in[7];
    const float* bhh1 = (const float*)d_in[8];
    const float* Wout = (const float*)d_in[9];
    const float* bout = (const float*)d_in[10];
    float* out = (float*)d_out;

    const int B = in_sizes[0] / (T_LEN*2);
    const int waves = (B + 31) / 32;
    const int blocks = (waves + 3) / 4;       // 4 waves per 256-thread block
    lstm_mfma32<<<blocks, 256, 0, stream>>>(x, Wih0, Whh0, bih0, bhh0,
                                            Wih1, Whh1, bih1, bhh1,
                                            Wout, bout, out, B);
}